// Round 1
// baseline (1622.561 us; speedup 1.0000x reference)
//
#include <hip/hip_runtime.h>
#include <math.h>

// Problem constants
#define kH  1024
#define kB  64
#define kS  256
#define kV  10000
#define kH3 3072

// ---------------- helpers ----------------
__device__ __forceinline__ float warp_sum(float v) {
#pragma unroll
  for (int off = 32; off > 0; off >>= 1) v += __shfl_down(v, off, 64);
  return v;  // valid on lane 0
}
__device__ __forceinline__ float warp_max_all(float v) {
#pragma unroll
  for (int off = 32; off > 0; off >>= 1) v = fmaxf(v, __shfl_xor(v, off, 64));
  return v;
}
__device__ __forceinline__ float warp_sum_all(float v) {
#pragma unroll
  for (int off = 32; off > 0; off >>= 1) v += __shfl_xor(v, off, 64);
  return v;
}
__device__ __forceinline__ float sigmoidf_(float x) { return 1.0f / (1.0f + __expf(-x)); }

// ---------------- GI = emb[seq] @ W_ih^T + b_ih  (64 x 3072) ----------------
// grid 768 x 256: one wave per output row r (3072 rows), loop over t=0..63.
__global__ __launch_bounds__(256) void k_gi(const int* __restrict__ seq,
    const float* __restrict__ emb, const float* __restrict__ W_ih,
    const float* __restrict__ b_ih, float* __restrict__ GI) {
  const int lane = threadIdx.x & 63;
  const int r = blockIdx.x * 4 + (threadIdx.x >> 6);
  const float4* wp = (const float4*)(W_ih + (size_t)r * kH) + lane * 4;
  const float4 w0 = wp[0], w1 = wp[1], w2 = wp[2], w3 = wp[3];
  const float br = b_ih[r];
  for (int t = 0; t < kB; ++t) {
    const int tok = seq[t];
    const float4* xp = (const float4*)(emb + (size_t)tok * kH) + lane * 4;
    const float4 x0 = xp[0], x1 = xp[1], x2 = xp[2], x3 = xp[3];
    float acc = w0.x*x0.x + w0.y*x0.y + w0.z*x0.z + w0.w*x0.w;
    acc += w1.x*x1.x + w1.y*x1.y + w1.z*x1.z + w1.w*x1.w;
    acc += w2.x*x2.x + w2.y*x2.y + w2.z*x2.z + w2.w*x2.w;
    acc += w3.x*x3.x + w3.y*x3.y + w3.z*x3.z + w3.w*x3.w;
    acc = warp_sum(acc);
    if (lane == 0) GI[(size_t)t * kH3 + r] = acc + br;
  }
}

// ---------------- Persistent GRU scan (64 sequential steps) ----------------
// grid 64 x 512 (all blocks resident). Block bid owns h[16*bid .. 16*bid+15].
// Wave w owns h-pair j = 16*bid + 2w: rows {j,j+1, H+j,H+j+1, 2H+j,2H+j+1} of
// W_hh live in registers (96 VGPR/thread). Cross-block handshake: producer
// stores h_new -> __threadfence (agent release) -> epoch[bid]=t+1 (agent
// atomic); consumers poll epochs (agent relaxed atomic), acquire-fence, then
// plain vector loads. 0xAA poison = negative signed int = "not ready".
__global__ __launch_bounds__(512) void k_gru(const float* __restrict__ h0,
    const float* __restrict__ W_hh, const float* __restrict__ b_hh,
    const float* __restrict__ GI, float* __restrict__ rnn,
    int* __restrict__ epoch) {
  const int tid  = threadIdx.x;
  const int lane = tid & 63;
  const int w    = tid >> 6;           // 0..7
  const int bid  = blockIdx.x;         // 0..63
  const int j    = bid * 16 + 2 * w;   // h-pair base

  float wv[6][16];
  {
    const int rows[6] = { j, j + 1, kH + j, kH + j + 1, 2 * kH + j, 2 * kH + j + 1 };
#pragma unroll
    for (int q = 0; q < 6; ++q) {
      const float4* p = (const float4*)(W_hh + (size_t)rows[q] * kH) + lane * 4;
#pragma unroll
      for (int c = 0; c < 4; ++c) {
        const float4 f = p[c];
        wv[q][c * 4 + 0] = f.x; wv[q][c * 4 + 1] = f.y;
        wv[q][c * 4 + 2] = f.z; wv[q][c * 4 + 3] = f.w;
      }
    }
  }
  const float2 bhr = *(const float2*)(b_hh + j);
  const float2 bhz = *(const float2*)(b_hh + kH + j);
  const float2 bhn = *(const float2*)(b_hh + 2 * kH + j);

  for (int t = 0; t < kB; ++t) {
    const float* hprev = (t == 0) ? h0 : (rnn + (size_t)(t - 1) * kH);
    if (t > 0) {
      while (true) {
        const int e = __hip_atomic_load(&epoch[lane], __ATOMIC_RELAXED,
                                        __HIP_MEMORY_SCOPE_AGENT);
        if (__all(e >= t)) break;
        __builtin_amdgcn_s_sleep(2);
      }
      __threadfence();  // acquire: invalidate stale L1/L2 before reading h
    }
    float hx[16];
    {
      const float4* hp = (const float4*)hprev + lane * 4;
#pragma unroll
      for (int c = 0; c < 4; ++c) {
        const float4 f = hp[c];
        hx[c * 4 + 0] = f.x; hx[c * 4 + 1] = f.y;
        hx[c * 4 + 2] = f.z; hx[c * 4 + 3] = f.w;
      }
    }
    float d[6];
#pragma unroll
    for (int q = 0; q < 6; ++q) {
      float acc = 0.f;
#pragma unroll
      for (int u = 0; u < 16; ++u) acc += wv[q][u] * hx[u];
      d[q] = acc;
    }
#pragma unroll
    for (int q = 0; q < 6; ++q) d[q] = warp_sum(d[q]);

    if (lane == 0) {
      const float2 gir = *(const float2*)(GI + (size_t)t * kH3 + j);
      const float2 giz = *(const float2*)(GI + (size_t)t * kH3 + kH + j);
      const float2 gin = *(const float2*)(GI + (size_t)t * kH3 + 2 * kH + j);
      // h_old for the z-blend: agent-scope atomic load (guaranteed fresh)
      const float ho0 = __hip_atomic_load(&hprev[j],     __ATOMIC_RELAXED,
                                          __HIP_MEMORY_SCOPE_AGENT);
      const float ho1 = __hip_atomic_load(&hprev[j + 1], __ATOMIC_RELAXED,
                                          __HIP_MEMORY_SCOPE_AGENT);
      const float r0 = sigmoidf_(gir.x + d[0] + bhr.x);
      const float r1 = sigmoidf_(gir.y + d[1] + bhr.y);
      const float z0 = sigmoidf_(giz.x + d[2] + bhz.x);
      const float z1 = sigmoidf_(giz.y + d[3] + bhz.y);
      const float n0 = tanhf(gin.x + r0 * (d[4] + bhn.x));
      const float n1 = tanhf(gin.y + r1 * (d[5] + bhn.y));
      float2 hn;
      hn.x = (1.f - z0) * n0 + z0 * ho0;
      hn.y = (1.f - z1) * n1 + z1 * ho1;
      *(float2*)(rnn + (size_t)t * kH + j) = hn;
    }
    __threadfence();   // release: drain + write back this step's h stores
    __syncthreads();   // all waves of block done before flag
    if (tid == 0)
      __hip_atomic_store(&epoch[bid], t + 1, __ATOMIC_RELAXED,
                         __HIP_MEMORY_SCOPE_AGENT);
  }
}

// ---------------- w2h[k] = sum_h v_attn[h] * W_attn[h][H+k] ----------------
// (softmax is shift-invariant: the h_bc half of cat and b_attn drop out)
// grid 256 x 256: block handles 4 columns.
__global__ __launch_bounds__(256) void k_w2h(const float* __restrict__ W_attn,
    const float* __restrict__ v_attn, float* __restrict__ w2h) {
  __shared__ float4 red[256];
  const int t  = threadIdx.x;
  const int k0 = kH + blockIdx.x * 4;  // absolute column in W_attn
  float ax = 0, ay = 0, az = 0, aw = 0;
  for (int h = t; h < kH; h += 256) {
    const float vh = v_attn[h];
    const float4 wq = *(const float4*)(W_attn + (size_t)h * 2048 + k0);
    ax += vh * wq.x; ay += vh * wq.y; az += vh * wq.z; aw += vh * wq.w;
  }
  red[t] = make_float4(ax, ay, az, aw);
  __syncthreads();
  for (int s = 128; s > 0; s >>= 1) {
    if (t < s) {
      const float4 a = red[t], b = red[t + s];
      red[t] = make_float4(a.x + b.x, a.y + b.y, a.z + b.z, a.w + b.w);
    }
    __syncthreads();
  }
  if (t == 0) *(float4*)(w2h + blockIdx.x * 4) = red[0];
}

// ---------------- scores[b][s] = enc[s][b][:] . w2h ----------------
// grid 4096 x 256: one wave per (b,s).
__global__ __launch_bounds__(256) void k_scores(const float* __restrict__ enc,
    const float* __restrict__ w2h, float* __restrict__ sc) {
  const int lane = threadIdx.x & 63;
  const int wg = blockIdx.x * 4 + (threadIdx.x >> 6);  // 0..16383
  const int b = wg & 63, s = wg >> 6;
  const float4* ep = (const float4*)(enc + ((size_t)s * kB + b) * kH) + lane * 4;
  const float4* wp = (const float4*)w2h + lane * 4;
  float acc = 0.f;
#pragma unroll
  for (int c = 0; c < 4; ++c) {
    const float4 e = ep[c], wq = wp[c];
    acc += e.x * wq.x + e.y * wq.y + e.z * wq.z + e.w * wq.w;
  }
  acc = warp_sum(acc);
  if (lane == 0) sc[b * kS + s] = acc;
}

// ---------------- softmax over s (64 rows of 256) -> attn output ----------------
__global__ __launch_bounds__(256) void k_softmax(const float* __restrict__ sc,
                                                 float* __restrict__ attn) {
  __shared__ float sm[4], ss[4];
  const int b = blockIdx.x, t = threadIdx.x, lane = t & 63, w = t >> 6;
  const float x = sc[b * kS + t];
  float m = warp_max_all(x);
  if (lane == 0) sm[w] = m;
  __syncthreads();
  m = fmaxf(fmaxf(sm[0], sm[1]), fmaxf(sm[2], sm[3]));
  const float e = __expf(x - m);
  float s = warp_sum_all(e);
  if (lane == 0) ss[w] = s;
  __syncthreads();
  s = ss[0] + ss[1] + ss[2] + ss[3];
  attn[b * kS + t] = e / s;
}

// ---------------- context partials: part[ch][b][h] = sum_{s in chunk} a*enc ----------------
// grid 256 x 256: blockIdx = ch*64 + b, 4 chunks of 64 s each.
__global__ __launch_bounds__(256) void k_context(const float* __restrict__ enc,
    const float* __restrict__ attn, float* __restrict__ part) {
  const int b  = blockIdx.x & 63;
  const int ch = blockIdx.x >> 6;
  const int h0 = threadIdx.x * 4;
  float ax = 0, ay = 0, az = 0, aw = 0;
  const int s0 = ch * 64;
  for (int s = s0; s < s0 + 64; ++s) {
    const float a = attn[b * kS + s];
    const float4 v = *(const float4*)(enc + ((size_t)s * kB + b) * kH + h0);
    ax += a * v.x; ay += a * v.y; az += a * v.z; aw += a * v.w;
  }
  *(float4*)(part + ((size_t)ch * kB + b) * kH + h0) =
      make_float4(ax, ay, az, aw);
}

// ---------------- context sum + hidden output copy ----------------
// grid 64 x 256.
__global__ __launch_bounds__(256) void k_ctxsum(const float* __restrict__ part,
    const float* __restrict__ rnn, float* __restrict__ ctx,
    float* __restrict__ hid) {
  const int b = blockIdx.x;
  const int h0 = threadIdx.x * 4;
  float4 s = *(const float4*)(part + ((size_t)0 * kB + b) * kH + h0);
#pragma unroll
  for (int c = 1; c < 4; ++c) {
    const float4 p = *(const float4*)(part + ((size_t)c * kB + b) * kH + h0);
    s.x += p.x; s.y += p.y; s.z += p.z; s.w += p.w;
  }
  *(float4*)(ctx + (size_t)b * kH + h0) = s;
  if (b < 4) {
    const int i = b * 256 + threadIdx.x;
    hid[i] = rnn[63 * kH + i];
  }
}

// ---------------- coT[i][b] = tanh([rnn,ctx][b] . W_concat[i] + b_concat[i]) ----------------
// grid 256 x 256: one wave per output row i; W row in registers; loop b.
// Writes TRANSPOSED (i-major) so k_out's b=lane loads are coalesced.
__global__ __launch_bounds__(256) void k_concat(const float* __restrict__ rnn,
    const float* __restrict__ ctx, const float* __restrict__ W_c,
    const float* __restrict__ b_c, float* __restrict__ coT) {
  const int lane = threadIdx.x & 63;
  const int i = blockIdx.x * 4 + (threadIdx.x >> 6);  // 0..1023
  float wreg[32];
  {
    const float4* wp = (const float4*)(W_c + (size_t)i * 2048) + lane * 8;
#pragma unroll
    for (int c = 0; c < 8; ++c) {
      const float4 f = wp[c];
      wreg[c * 4 + 0] = f.x; wreg[c * 4 + 1] = f.y;
      wreg[c * 4 + 2] = f.z; wreg[c * 4 + 3] = f.w;
    }
  }
  const float bc = b_c[i];
  const int jcol = lane * 32;  // column in the 2048-wide concat input
  const float* xbase = (jcol < kH) ? (rnn + jcol) : (ctx + (jcol - kH));
  for (int b = 0; b < kB; ++b) {
    const float* xr = xbase + (size_t)b * kH;
    float acc = 0.f;
#pragma unroll
    for (int c = 0; c < 8; ++c) {
      const float4 x = *(const float4*)(xr + c * 4);
      acc += wreg[c * 4 + 0] * x.x + wreg[c * 4 + 1] * x.y +
             wreg[c * 4 + 2] * x.z + wreg[c * 4 + 3] * x.w;
    }
    acc = warp_sum(acc);
    if (lane == 0) coT[(size_t)i * kB + b] = tanhf(acc + bc);
  }
}

// ---------------- output[b][v] = coT[:,b] . W_out[v] + b_out[v] ----------------
// grid 250 x 256: 1000 waves, 10 v-rows per wave, lane = b.
// W_out rows via wave-uniform (scalar) loads; coT reads coalesced (256B/row).
__global__ __launch_bounds__(256) void k_out(const float* __restrict__ coT,
    const float* __restrict__ W_out, const float* __restrict__ b_out,
    float* __restrict__ out) {
  const int lane = threadIdx.x & 63;
  int wg = blockIdx.x * 4 + (threadIdx.x >> 6);
  wg = __builtin_amdgcn_readfirstlane(wg);   // force wave-uniform -> s_loads
  const int v0 = wg * 10;
  float acc[10];
#pragma unroll
  for (int i = 0; i < 10; ++i) acc[i] = 0.f;
  for (int h = 0; h < kH; h += 4) {
    const float x0 = coT[(h + 0) * kB + lane];
    const float x1 = coT[(h + 1) * kB + lane];
    const float x2 = coT[(h + 2) * kB + lane];
    const float x3 = coT[(h + 3) * kB + lane];
#pragma unroll
    for (int i = 0; i < 10; ++i) {
      const float4 wq = *(const float4*)(W_out + (size_t)(v0 + i) * kH + h);
      acc[i] += wq.x * x0 + wq.y * x1 + wq.z * x2 + wq.w * x3;
    }
  }
#pragma unroll
  for (int i = 0; i < 10; ++i)
    out[(size_t)lane * kV + v0 + i] = acc[i] + b_out[v0 + i];
}

// ---------------- launcher ----------------
extern "C" void kernel_launch(void* const* d_in, const int* in_sizes, int n_in,
                              void* d_out, int out_size, void* d_ws,
                              size_t ws_size, hipStream_t stream) {
  const int*   seq    = (const int*)  d_in[0];
  const float* h0     = (const float*)d_in[1];
  const float* enc    = (const float*)d_in[2];
  const float* emb    = (const float*)d_in[3];
  const float* W_ih   = (const float*)d_in[4];
  const float* W_hh   = (const float*)d_in[5];
  const float* b_ih   = (const float*)d_in[6];
  const float* b_hh   = (const float*)d_in[7];
  const float* W_attn = (const float*)d_in[8];
  // d_in[9] = b_attn: drops out of softmax (shift invariance)
  const float* v_attn = (const float*)d_in[10];
  const float* W_conc = (const float*)d_in[11];
  const float* b_conc = (const float*)d_in[12];
  const float* W_outp = (const float*)d_in[13];
  const float* b_outp = (const float*)d_in[14];

  float* out      = (float*)d_out;           // (B,V) = 640000
  float* out_hid  = out + 640000;            // (1,1,H) = 1024
  float* out_attn = out + 641024;            // (B,1,S) = 16384

  float* ws   = (float*)d_ws;
  float* GI   = ws;              // 64*3072   = 196608
  float* RNN  = ws + 196608;     // 64*1024   =  65536
  int*   EPO  = (int*)(ws + 262144);  // 64 ints (poison 0xAA.. < 0 = not ready)
  float* W2H  = ws + 262272;     // 1024
  float* SC   = ws + 263296;     // 64*256    =  16384
  float* PART = ws + 279680;     // 4*64*1024 = 262144
  float* CTX  = ws + 541824;     // 64*1024   =  65536
  float* COT  = ws + 607360;     // 1024*64   =  65536  (end 672896 floats)

  k_gi<<<768, 256, 0, stream>>>(seq, emb, W_ih, b_ih, GI);
  k_gru<<<64, 512, 0, stream>>>(h0, W_hh, b_hh, GI, RNN, EPO);
  k_w2h<<<256, 256, 0, stream>>>(W_attn, v_attn, W2H);
  k_scores<<<4096, 256, 0, stream>>>(enc, W2H, SC);
  k_softmax<<<64, 256, 0, stream>>>(SC, out_attn);
  k_context<<<256, 256, 0, stream>>>(enc, out_attn, PART);
  k_ctxsum<<<64, 256, 0, stream>>>(PART, RNN, CTX, out_hid);
  k_concat<<<256, 256, 0, stream>>>(RNN, CTX, W_conc, b_conc, COT);
  k_out<<<250, 256, 0, stream>>>(COT, W_outp, b_outp, out);
}

// Round 2
// 711.013 us; speedup vs baseline: 2.2820x; 2.2820x over previous
//
#include <hip/hip_runtime.h>
#include <math.h>

// Problem constants
#define kH  1024
#define kB  64
#define kS  256
#define kV  10000
#define kH3 3072

// ---------------- helpers ----------------
__device__ __forceinline__ float warp_sum(float v) {
#pragma unroll
  for (int off = 32; off > 0; off >>= 1) v += __shfl_down(v, off, 64);
  return v;  // valid on lane 0
}
__device__ __forceinline__ float warp_max_all(float v) {
#pragma unroll
  for (int off = 32; off > 0; off >>= 1) v = fmaxf(v, __shfl_xor(v, off, 64));
  return v;
}
__device__ __forceinline__ float warp_sum_all(float v) {
#pragma unroll
  for (int off = 32; off > 0; off >>= 1) v += __shfl_xor(v, off, 64);
  return v;
}
__device__ __forceinline__ float sigmoidf_(float x) { return 1.0f / (1.0f + __expf(-x)); }

// ---------------- GI = emb[seq] @ W_ih^T + b_ih  (64 x 3072) ----------------
// grid 768 x 256: one wave per output row r (3072 rows), loop over t=0..63.
__global__ __launch_bounds__(256) void k_gi(const int* __restrict__ seq,
    const float* __restrict__ emb, const float* __restrict__ W_ih,
    const float* __restrict__ b_ih, float* __restrict__ GI) {
  const int lane = threadIdx.x & 63;
  const int r = blockIdx.x * 4 + (threadIdx.x >> 6);
  const float4* wp = (const float4*)(W_ih + (size_t)r * kH) + lane * 4;
  const float4 w0 = wp[0], w1 = wp[1], w2 = wp[2], w3 = wp[3];
  const float br = b_ih[r];
  for (int t = 0; t < kB; ++t) {
    const int tok = seq[t];
    const float4* xp = (const float4*)(emb + (size_t)tok * kH) + lane * 4;
    const float4 x0 = xp[0], x1 = xp[1], x2 = xp[2], x3 = xp[3];
    float acc = w0.x*x0.x + w0.y*x0.y + w0.z*x0.z + w0.w*x0.w;
    acc += w1.x*x1.x + w1.y*x1.y + w1.z*x1.z + w1.w*x1.w;
    acc += w2.x*x2.x + w2.y*x2.y + w2.z*x2.z + w2.w*x2.w;
    acc += w3.x*x3.x + w3.y*x3.y + w3.z*x3.z + w3.w*x3.w;
    acc = warp_sum(acc);
    if (lane == 0) GI[(size_t)t * kH3 + r] = acc + br;
  }
}

// ---------------- Persistent GRU scan (64 sequential steps) ----------------
// grid 64 x 512 (all resident: 64 blocks << 256 CUs). Block bid owns
// h[16*bid..16*bid+15]; wave w owns pair j = 16*bid + 2w.
//
// Handshake: NO fences. Producer packs (tag = t+1, float bits) into one u64
// and publishes with a relaxed agent-scope atomic store into the per-step
// slot step[t][j]. Consumers do relaxed agent-scope atomic loads and spin
// until the tag matches — the 64-bit single-location atomicity carries the
// data with its readiness flag, so no cache-maintenance ops are needed.
// ws poison 0xAAAAAAAA never matches tags 1..64. Each block stages h_prev
// into LDS once (2 slots/thread), then all 8 waves read LDS.
__global__ __launch_bounds__(512) void k_gru(const float* __restrict__ h0,
    const float* __restrict__ W_hh, const float* __restrict__ b_hh,
    const float* __restrict__ GI, float* __restrict__ rnn,
    unsigned long long* __restrict__ step) {
  __shared__ float hs[kH];
  const int tid  = threadIdx.x;
  const int lane = tid & 63;
  const int w    = tid >> 6;           // 0..7
  const int bid  = blockIdx.x;         // 0..63
  const int j    = bid * 16 + 2 * w;   // h-pair base

  // Weights in registers, laid out to match hx[u] = h[u*64 + lane]:
  // wv[q][u] = W_hh[rows[q]][u*64 + lane]  (coalesced load per (q,u))
  float wv[6][16];
  {
    const int rows[6] = { j, j + 1, kH + j, kH + j + 1, 2 * kH + j, 2 * kH + j + 1 };
#pragma unroll
    for (int q = 0; q < 6; ++q) {
      const float* base = W_hh + (size_t)rows[q] * kH + lane;
#pragma unroll
      for (int u = 0; u < 16; ++u) wv[q][u] = base[u * 64];
    }
  }
  const float2 bhr = *(const float2*)(b_hh + j);
  const float2 bhz = *(const float2*)(b_hh + kH + j);
  const float2 bhn = *(const float2*)(b_hh + 2 * kH + j);

  for (int t = 0; t < kB; ++t) {
    // ---- stage h_prev into LDS (2 slots per thread) ----
    if (t == 0) {
      ((float2*)hs)[tid] = ((const float2*)h0)[tid];
    } else {
      const unsigned long long* sb = step + (size_t)(t - 1) * kH;
      const int i0 = tid * 2, i1 = i0 + 1;
      const unsigned want = (unsigned)t;  // producer of step t-1 wrote tag t
      bool d0 = false, d1 = false;
      float v0 = 0.f, v1 = 0.f;
      while (true) {
        if (!d0) {
          const unsigned long long x = __hip_atomic_load(&sb[i0],
              __ATOMIC_RELAXED, __HIP_MEMORY_SCOPE_AGENT);
          if ((unsigned)(x >> 32) == want) { v0 = __uint_as_float((unsigned)x); d0 = true; }
        }
        if (!d1) {
          const unsigned long long x = __hip_atomic_load(&sb[i1],
              __ATOMIC_RELAXED, __HIP_MEMORY_SCOPE_AGENT);
          if ((unsigned)(x >> 32) == want) { v1 = __uint_as_float((unsigned)x); d1 = true; }
        }
        if (d0 && d1) break;
        __builtin_amdgcn_s_sleep(1);
      }
      hs[i0] = v0; hs[i1] = v1;
    }
    __syncthreads();

    // ---- hx[u] = h_prev[u*64 + lane]  (conflict-free LDS b32 reads) ----
    float hx[16];
#pragma unroll
    for (int u = 0; u < 16; ++u) hx[u] = hs[u * 64 + lane];

    float d[6];
#pragma unroll
    for (int q = 0; q < 6; ++q) {
      float acc = 0.f;
#pragma unroll
      for (int u = 0; u < 16; ++u) acc += wv[q][u] * hx[u];
      d[q] = acc;
    }
#pragma unroll
    for (int q = 0; q < 6; ++q) d[q] = warp_sum(d[q]);

    if (lane == 0) {
      const float2 gir = *(const float2*)(GI + (size_t)t * kH3 + j);
      const float2 giz = *(const float2*)(GI + (size_t)t * kH3 + kH + j);
      const float2 gin = *(const float2*)(GI + (size_t)t * kH3 + 2 * kH + j);
      const float ho0 = hs[j], ho1 = hs[j + 1];  // exact h_prev from LDS
      const float r0 = sigmoidf_(gir.x + d[0] + bhr.x);
      const float r1 = sigmoidf_(gir.y + d[1] + bhr.y);
      const float z0 = sigmoidf_(giz.x + d[2] + bhz.x);
      const float z1 = sigmoidf_(giz.y + d[3] + bhz.y);
      const float n0 = tanhf(gin.x + r0 * (d[4] + bhn.x));
      const float n1 = tanhf(gin.y + r1 * (d[5] + bhn.y));
      float2 hn;
      hn.x = (1.f - z0) * n0 + z0 * ho0;
      hn.y = (1.f - z1) * n1 + z1 * ho1;
      *(float2*)(rnn + (size_t)t * kH + j) = hn;  // for downstream kernels
      const unsigned long long tagw = ((unsigned long long)(t + 1)) << 32;
      __hip_atomic_store(&step[(size_t)t * kH + j], tagw | __float_as_uint(hn.x),
                         __ATOMIC_RELAXED, __HIP_MEMORY_SCOPE_AGENT);
      __hip_atomic_store(&step[(size_t)t * kH + j + 1], tagw | __float_as_uint(hn.y),
                         __ATOMIC_RELAXED, __HIP_MEMORY_SCOPE_AGENT);
    }
    __syncthreads();  // all waves done reading hs before next stage overwrites
  }
}

// ---------------- w2h[k] = sum_h v_attn[h] * W_attn[h][H+k] ----------------
// (softmax is shift-invariant: the h_bc half of cat and b_attn drop out)
__global__ __launch_bounds__(256) void k_w2h(const float* __restrict__ W_attn,
    const float* __restrict__ v_attn, float* __restrict__ w2h) {
  __shared__ float4 red[256];
  const int t  = threadIdx.x;
  const int k0 = kH + blockIdx.x * 4;  // absolute column in W_attn
  float ax = 0, ay = 0, az = 0, aw = 0;
  for (int h = t; h < kH; h += 256) {
    const float vh = v_attn[h];
    const float4 wq = *(const float4*)(W_attn + (size_t)h * 2048 + k0);
    ax += vh * wq.x; ay += vh * wq.y; az += vh * wq.z; aw += vh * wq.w;
  }
  red[t] = make_float4(ax, ay, az, aw);
  __syncthreads();
  for (int s = 128; s > 0; s >>= 1) {
    if (t < s) {
      const float4 a = red[t], b = red[t + s];
      red[t] = make_float4(a.x + b.x, a.y + b.y, a.z + b.z, a.w + b.w);
    }
    __syncthreads();
  }
  if (t == 0) *(float4*)(w2h + blockIdx.x * 4) = red[0];
}

// ---------------- scores[b][s] = enc[s][b][:] . w2h ----------------
__global__ __launch_bounds__(256) void k_scores(const float* __restrict__ enc,
    const float* __restrict__ w2h, float* __restrict__ sc) {
  const int lane = threadIdx.x & 63;
  const int wg = blockIdx.x * 4 + (threadIdx.x >> 6);  // 0..16383
  const int b = wg & 63, s = wg >> 6;
  const float4* ep = (const float4*)(enc + ((size_t)s * kB + b) * kH) + lane * 4;
  const float4* wp = (const float4*)w2h + lane * 4;
  float acc = 0.f;
#pragma unroll
  for (int c = 0; c < 4; ++c) {
    const float4 e = ep[c], wq = wp[c];
    acc += e.x * wq.x + e.y * wq.y + e.z * wq.z + e.w * wq.w;
  }
  acc = warp_sum(acc);
  if (lane == 0) sc[b * kS + s] = acc;
}

// ---------------- softmax over s (64 rows of 256) -> attn output ----------------
__global__ __launch_bounds__(256) void k_softmax(const float* __restrict__ sc,
                                                 float* __restrict__ attn) {
  __shared__ float sm[4], ss[4];
  const int b = blockIdx.x, t = threadIdx.x, lane = t & 63, w = t >> 6;
  const float x = sc[b * kS + t];
  float m = warp_max_all(x);
  if (lane == 0) sm[w] = m;
  __syncthreads();
  m = fmaxf(fmaxf(sm[0], sm[1]), fmaxf(sm[2], sm[3]));
  const float e = __expf(x - m);
  float s = warp_sum_all(e);
  if (lane == 0) ss[w] = s;
  __syncthreads();
  s = ss[0] + ss[1] + ss[2] + ss[3];
  attn[b * kS + t] = e / s;
}

// ---------------- context partials ----------------
__global__ __launch_bounds__(256) void k_context(const float* __restrict__ enc,
    const float* __restrict__ attn, float* __restrict__ part) {
  const int b  = blockIdx.x & 63;
  const int ch = blockIdx.x >> 6;
  const int h0 = threadIdx.x * 4;
  float ax = 0, ay = 0, az = 0, aw = 0;
  const int s0 = ch * 64;
  for (int s = s0; s < s0 + 64; ++s) {
    const float a = attn[b * kS + s];
    const float4 v = *(const float4*)(enc + ((size_t)s * kB + b) * kH + h0);
    ax += a * v.x; ay += a * v.y; az += a * v.z; aw += a * v.w;
  }
  *(float4*)(part + ((size_t)ch * kB + b) * kH + h0) =
      make_float4(ax, ay, az, aw);
}

// ---------------- context sum + hidden output copy ----------------
__global__ __launch_bounds__(256) void k_ctxsum(const float* __restrict__ part,
    const float* __restrict__ rnn, float* __restrict__ ctx,
    float* __restrict__ hid) {
  const int b = blockIdx.x;
  const int h0 = threadIdx.x * 4;
  float4 s = *(const float4*)(part + ((size_t)0 * kB + b) * kH + h0);
#pragma unroll
  for (int c = 1; c < 4; ++c) {
    const float4 p = *(const float4*)(part + ((size_t)c * kB + b) * kH + h0);
    s.x += p.x; s.y += p.y; s.z += p.z; s.w += p.w;
  }
  *(float4*)(ctx + (size_t)b * kH + h0) = s;
  if (b < 4) {
    const int i = b * 256 + threadIdx.x;
    hid[i] = rnn[63 * kH + i];
  }
}

// ---------------- coT[i][b] = tanh([rnn,ctx][b] . W_concat[i] + b_c[i]) ----------------
__global__ __launch_bounds__(256) void k_concat(const float* __restrict__ rnn,
    const float* __restrict__ ctx, const float* __restrict__ W_c,
    const float* __restrict__ b_c, float* __restrict__ coT) {
  const int lane = threadIdx.x & 63;
  const int i = blockIdx.x * 4 + (threadIdx.x >> 6);  // 0..1023
  float wreg[32];
  {
    const float4* wp = (const float4*)(W_c + (size_t)i * 2048) + lane * 8;
#pragma unroll
    for (int c = 0; c < 8; ++c) {
      const float4 f = wp[c];
      wreg[c * 4 + 0] = f.x; wreg[c * 4 + 1] = f.y;
      wreg[c * 4 + 2] = f.z; wreg[c * 4 + 3] = f.w;
    }
  }
  const float bc = b_c[i];
  const int jcol = lane * 32;
  const float* xbase = (jcol < kH) ? (rnn + jcol) : (ctx + (jcol - kH));
  for (int b = 0; b < kB; ++b) {
    const float* xr = xbase + (size_t)b * kH;
    float acc = 0.f;
#pragma unroll
    for (int c = 0; c < 8; ++c) {
      const float4 x = *(const float4*)(xr + c * 4);
      acc += wreg[c * 4 + 0] * x.x + wreg[c * 4 + 1] * x.y +
             wreg[c * 4 + 2] * x.z + wreg[c * 4 + 3] * x.w;
    }
    acc = warp_sum(acc);
    if (lane == 0) coT[(size_t)i * kB + b] = tanhf(acc + bc);
  }
}

// ---------------- output[b][v] = coT[:,b] . W_out[v] + b_out[v] ----------------
__global__ __launch_bounds__(256) void k_out(const float* __restrict__ coT,
    const float* __restrict__ W_out, const float* __restrict__ b_out,
    float* __restrict__ out) {
  const int lane = threadIdx.x & 63;
  int wg = blockIdx.x * 4 + (threadIdx.x >> 6);
  wg = __builtin_amdgcn_readfirstlane(wg);   // wave-uniform -> s_loads
  const int v0 = wg * 10;
  float acc[10];
#pragma unroll
  for (int i = 0; i < 10; ++i) acc[i] = 0.f;
  for (int h = 0; h < kH; h += 4) {
    const float x0 = coT[(h + 0) * kB + lane];
    const float x1 = coT[(h + 1) * kB + lane];
    const float x2 = coT[(h + 2) * kB + lane];
    const float x3 = coT[(h + 3) * kB + lane];
#pragma unroll
    for (int i = 0; i < 10; ++i) {
      const float4 wq = *(const float4*)(W_out + (size_t)(v0 + i) * kH + h);
      acc[i] += wq.x * x0 + wq.y * x1 + wq.z * x2 + wq.w * x3;
    }
  }
#pragma unroll
  for (int i = 0; i < 10; ++i)
    out[(size_t)lane * kV + v0 + i] = acc[i] + b_out[v0 + i];
}

// ---------------- launcher ----------------
extern "C" void kernel_launch(void* const* d_in, const int* in_sizes, int n_in,
                              void* d_out, int out_size, void* d_ws,
                              size_t ws_size, hipStream_t stream) {
  const int*   seq    = (const int*)  d_in[0];
  const float* h0     = (const float*)d_in[1];
  const float* enc    = (const float*)d_in[2];
  const float* emb    = (const float*)d_in[3];
  const float* W_ih   = (const float*)d_in[4];
  const float* W_hh   = (const float*)d_in[5];
  const float* b_ih   = (const float*)d_in[6];
  const float* b_hh   = (const float*)d_in[7];
  const float* W_attn = (const float*)d_in[8];
  // d_in[9] = b_attn: drops out of softmax (shift invariance)
  const float* v_attn = (const float*)d_in[10];
  const float* W_conc = (const float*)d_in[11];
  const float* b_conc = (const float*)d_in[12];
  const float* W_outp = (const float*)d_in[13];
  const float* b_outp = (const float*)d_in[14];

  float* out      = (float*)d_out;           // (B,V) = 640000
  float* out_hid  = out + 640000;            // (1,1,H) = 1024
  float* out_attn = out + 641024;            // (B,1,S) = 16384

  float* ws = (float*)d_ws;
  float* GI   = ws;                      // 64*3072   = 196608
  float* RNN  = ws + 196608;             // 64*1024   =  65536
  unsigned long long* STEP =
      (unsigned long long*)(ws + 262144);  // 64*1024 u64 = 131072 floats
  float* W2H  = ws + 393216;             // 1024
  float* SC   = ws + 394240;             // 64*256    =  16384
  float* PART = ws + 410624;             // 4*64*1024 = 262144
  float* CTX  = ws + 672768;             // 64*1024   =  65536
  float* COT  = ws + 738304;             // 1024*64   =  65536 (end 803840 floats)

  k_gi<<<768, 256, 0, stream>>>(seq, emb, W_ih, b_ih, GI);
  k_gru<<<64, 512, 0, stream>>>(h0, W_hh, b_hh, GI, RNN, STEP);
  k_w2h<<<256, 256, 0, stream>>>(W_attn, v_attn, W2H);
  k_scores<<<4096, 256, 0, stream>>>(enc, W2H, SC);
  k_softmax<<<64, 256, 0, stream>>>(SC, out_attn);
  k_context<<<256, 256, 0, stream>>>(enc, out_attn, PART);
  k_ctxsum<<<64, 256, 0, stream>>>(PART, RNN, CTX, out_hid);
  k_concat<<<256, 256, 0, stream>>>(RNN, CTX, W_conc, b_conc, COT);
  k_out<<<250, 256, 0, stream>>>(COT, W_outp, b_outp, out);
}